// Round 1
// baseline (670.978 us; speedup 1.0000x reference)
//
#include <hip/hip_runtime.h>
#include <cfloat>
#include <cstdint>

#define N_NODES 50000
#define N_EDGES 600000
#define HDIM    128
#define NGRAPH  2000
#define BN_EPS  1e-5f

// ---------------- CSR build ----------------

__global__ void k_init(int* degi, int* seg_s, int* seg_e) {
    int i = blockIdx.x * 256 + threadIdx.x;
    if (i < N_NODES) degi[i] = 1;                  // self-loop
    if (i < NGRAPH) { seg_s[i] = 0x7FFFFFFF; seg_e[i] = 0; }
}

__global__ void k_count(const int* __restrict__ ei, int* degi) {
    int e = blockIdx.x * 256 + threadIdx.x;
    if (e < N_EDGES) atomicAdd(&degi[ei[N_EDGES + e]], 1);   // col = targets
}

__global__ void k_dinv(const int* __restrict__ degi, float* dinv) {
    int i = blockIdx.x * 256 + threadIdx.x;
    if (i < N_NODES) dinv[i] = rsqrtf((float)degi[i]);
}

// two-level exclusive scan of degi -> ptr[0..N]
__global__ void k_scanA(const int* __restrict__ degi, int* ptr, int* bsum) {
    __shared__ int t[256];
    int i = blockIdx.x * 256 + threadIdx.x;
    int v = (i < N_NODES) ? degi[i] : 0;
    t[threadIdx.x] = v; __syncthreads();
    for (int off = 1; off < 256; off <<= 1) {
        int a = (threadIdx.x >= off) ? t[threadIdx.x - off] : 0;
        __syncthreads();
        t[threadIdx.x] += a;
        __syncthreads();
    }
    if (i < N_NODES) ptr[i + 1] = t[threadIdx.x];   // within-chunk inclusive
    if (threadIdx.x == 255) bsum[blockIdx.x] = t[255];
}

__global__ void k_scanB(const int* __restrict__ bsum, int* boff, int nb) {
    __shared__ int t[256];
    int i = threadIdx.x;
    int v = (i < nb) ? bsum[i] : 0;
    t[i] = v; __syncthreads();
    for (int off = 1; off < 256; off <<= 1) {
        int a = (i >= off) ? t[i - off] : 0;
        __syncthreads();
        t[i] += a;
        __syncthreads();
    }
    if (i < nb) boff[i] = t[i] - v;                 // exclusive
}

__global__ void k_scanC(int* ptr, const int* __restrict__ boff, int* cursor) {
    int i = blockIdx.x * 256 + threadIdx.x;
    if (i < N_NODES) {
        int val = ptr[i + 1] + boff[blockIdx.x];
        ptr[i + 1] = val;
        if (i + 1 < N_NODES) cursor[i + 1] = val;
    }
    if (i == 0) { ptr[0] = 0; cursor[0] = 0; }
}

__global__ void k_fill(const int* __restrict__ ei, const float* __restrict__ dinv,
                       int* cursor, int* crow, float* cnrm) {
    int e = blockIdx.x * 256 + threadIdx.x;
    if (e < N_EDGES) {
        int r = ei[e], c = ei[N_EDGES + e];
        int pos = atomicAdd(&cursor[c], 1);
        crow[pos] = r; cnrm[pos] = dinv[r] * dinv[c];
    } else if (e < N_EDGES + N_NODES) {
        int v = e - N_EDGES;
        int pos = atomicAdd(&cursor[v], 1);
        crow[pos] = v; cnrm[pos] = dinv[v] * dinv[v];
    }
}

__global__ void k_seg(const int* __restrict__ batch, int* seg_s, int* seg_e) {
    int i = blockIdx.x * 256 + threadIdx.x;
    if (i < N_NODES) {
        int g = batch[i];
        atomicMin(&seg_s[g], i);
        atomicMax(&seg_e[g], i + 1);
    }
}

// ---------------- dense transform: hout = hin @ W ----------------
// 512 threads = 8 waves; each wave owns 8 nodes; each lane owns channels (lane, lane+64).

__global__ __launch_bounds__(512) void k_transform(const float* __restrict__ hin,
                                                   const float* __restrict__ W,
                                                   float* __restrict__ hout) {
    __shared__ float Wl[HDIM * HDIM];
    {
        const float4* W4 = (const float4*)W;
        float4* Wl4 = (float4*)Wl;
        for (int i = threadIdx.x; i < HDIM * HDIM / 4; i += 512) Wl4[i] = W4[i];
    }
    __syncthreads();
    int wave = threadIdx.x >> 6, lane = threadIdx.x & 63;
    int nb = blockIdx.x * 64 + wave * 8;
    int c0 = lane, c1 = lane + 64;

    const float* hp[8];
#pragma unroll
    for (int j = 0; j < 8; j++) {
        int nidx = nb + j; if (nidx >= N_NODES) nidx = N_NODES - 1;
        hp[j] = hin + (size_t)nidx * HDIM;
    }
    float acc0[8], acc1[8];
#pragma unroll
    for (int j = 0; j < 8; j++) { acc0[j] = 0.f; acc1[j] = 0.f; }

    for (int k = 0; k < HDIM; k++) {
        float w0 = Wl[k * HDIM + c0];
        float w1 = Wl[k * HDIM + c1];
#pragma unroll
        for (int j = 0; j < 8; j++) {
            float hv = hp[j][k];
            acc0[j] += hv * w0;
            acc1[j] += hv * w1;
        }
    }
#pragma unroll
    for (int j = 0; j < 8; j++) {
        int nidx = nb + j;
        if (nidx < N_NODES) {
            hout[(size_t)nidx * HDIM + c0] = acc0[j];
            hout[(size_t)nidx * HDIM + c1] = acc1[j];
        }
    }
}

// ---------------- aggregate + bias + BN + ReLU ----------------
// 256 threads = 2 nodes per block; thread = one channel of one node.

__global__ __launch_bounds__(256) void k_aggregate(const float* __restrict__ hT,
                                                   const int* __restrict__ ptr,
                                                   const int* __restrict__ crow,
                                                   const float* __restrict__ cnrm,
                                                   const float* __restrict__ bias,
                                                   const float* __restrict__ bng,
                                                   const float* __restrict__ bnb,
                                                   const float* __restrict__ bnm,
                                                   const float* __restrict__ bnv,
                                                   float* __restrict__ hout) {
    int v = blockIdx.x * 2 + (threadIdx.x >> 7);
    int c = threadIdx.x & 127;
    if (v >= N_NODES) return;
    float acc = 0.f;
    int e0 = ptr[v], e1 = ptr[v + 1];
    for (int j = e0; j < e1; j++) {
        acc += cnrm[j] * hT[(size_t)crow[j] * HDIM + c];
    }
    acc += bias[c];
    float y = (acc - bnm[c]) * rsqrtf(bnv[c] + BN_EPS) * bng[c] + bnb[c];
    hout[(size_t)v * HDIM + c] = fmaxf(y, 0.f);
}

// ---------------- pool (mean|max|sum) + MLP ----------------

__global__ __launch_bounds__(128) void k_pool(const float* __restrict__ h,
                                              const int* __restrict__ seg_s,
                                              const int* __restrict__ seg_e,
                                              const float* __restrict__ l1W,
                                              const float* __restrict__ l1b,
                                              const float* __restrict__ l2W,
                                              const float* __restrict__ l2b,
                                              float* __restrict__ out) {
    __shared__ float z[3 * HDIM];
    __shared__ float red[2];
    int g = blockIdx.x, c = threadIdx.x;
    int s = seg_s[g], e = seg_e[g];
    float sum = 0.f, mx = -FLT_MAX;
    for (int i = s; i < e; i++) {
        float val = h[(size_t)i * HDIM + c];
        sum += val;
        mx = fmaxf(mx, val);
    }
    int cnt = (s < e) ? (e - s) : 0;
    if (cnt == 0) { mx = 0.f; sum = 0.f; }
    float mean = sum / (float)(cnt > 1 ? cnt : 1);
    z[c] = mean; z[HDIM + c] = mx; z[2 * HDIM + c] = sum;
    __syncthreads();
    float o = l1b[c];
    for (int k = 0; k < 3 * HDIM; k++) o += z[k] * l1W[k * HDIM + c];
    o = fmaxf(o, 0.f);
    float p = o * l2W[c];
#pragma unroll
    for (int off = 32; off; off >>= 1) p += __shfl_down(p, off, 64);
    if ((c & 63) == 0) red[c >> 6] = p;
    __syncthreads();
    if (c == 0) out[g] = red[0] + red[1] + l2b[0];
}

// ---------------- launch ----------------

extern "C" void kernel_launch(void* const* d_in, const int* in_sizes, int n_in,
                              void* d_out, int out_size, void* d_ws, size_t ws_size,
                              hipStream_t stream) {
    const float* x   = (const float*)d_in[0];
    const int*   ei  = (const int*)d_in[1];
    const int*   bat = (const int*)d_in[2];
    const float* W1  = (const float*)d_in[3];
    const float* b1  = (const float*)d_in[4];
    const float* W2  = (const float*)d_in[5];
    const float* b2  = (const float*)d_in[6];
    const float* W3  = (const float*)d_in[7];
    const float* b3  = (const float*)d_in[8];
    const float* bng = (const float*)d_in[9];
    const float* bnb = (const float*)d_in[10];
    const float* bnm = (const float*)d_in[11];
    const float* bnv = (const float*)d_in[12];
    const float* l1W = (const float*)d_in[13];
    const float* l1b = (const float*)d_in[14];
    const float* l2W = (const float*)d_in[15];
    const float* l2b = (const float*)d_in[16];
    float* out = (float*)d_out;

    char* ws = (char*)d_ws;
    size_t off = 0;
    auto alloc = [&](size_t bytes) -> char* {
        char* p = ws + off;
        off = (off + bytes + 255) & ~(size_t)255;
        return p;
    };
    int*   degi   = (int*)alloc((size_t)N_NODES * 4);
    float* dinv   = (float*)alloc((size_t)N_NODES * 4);
    int*   ptr    = (int*)alloc((size_t)(N_NODES + 1) * 4);
    int*   cursor = (int*)alloc((size_t)N_NODES * 4);
    int*   bsum   = (int*)alloc(256 * 4);
    int*   boff   = (int*)alloc(256 * 4);
    int*   seg_s  = (int*)alloc((size_t)NGRAPH * 4);
    int*   seg_e  = (int*)alloc((size_t)NGRAPH * 4);
    int*   crow   = (int*)alloc((size_t)(N_EDGES + N_NODES) * 4);
    float* cnrm   = (float*)alloc((size_t)(N_EDGES + N_NODES) * 4);
    float* hA     = (float*)alloc((size_t)N_NODES * HDIM * 4);
    float* hB     = (float*)alloc((size_t)N_NODES * HDIM * 4);
    (void)ws_size;

    int nblk = (N_NODES + 255) / 256;  // 196

    k_init<<<nblk, 256, 0, stream>>>(degi, seg_s, seg_e);
    k_count<<<(N_EDGES + 255) / 256, 256, 0, stream>>>(ei, degi);
    k_dinv<<<nblk, 256, 0, stream>>>(degi, dinv);
    k_scanA<<<nblk, 256, 0, stream>>>(degi, ptr, bsum);
    k_scanB<<<1, 256, 0, stream>>>(bsum, boff, nblk);
    k_scanC<<<nblk, 256, 0, stream>>>(ptr, boff, cursor);
    k_fill<<<(N_EDGES + N_NODES + 255) / 256, 256, 0, stream>>>(ei, dinv, cursor, crow, cnrm);
    k_seg<<<nblk, 256, 0, stream>>>(bat, seg_s, seg_e);

    int tb = (N_NODES + 63) / 64;  // 782
    int ab = (N_NODES + 1) / 2;    // 25000

    k_transform<<<tb, 512, 0, stream>>>(x, W1, hA);
    k_aggregate<<<ab, 256, 0, stream>>>(hA, ptr, crow, cnrm, b1,
                                        bng + 0, bnb + 0, bnm + 0, bnv + 0, hB);
    k_transform<<<tb, 512, 0, stream>>>(hB, W2, hA);
    k_aggregate<<<ab, 256, 0, stream>>>(hA, ptr, crow, cnrm, b2,
                                        bng + HDIM, bnb + HDIM, bnm + HDIM, bnv + HDIM, hB);
    k_transform<<<tb, 512, 0, stream>>>(hB, W3, hA);
    k_aggregate<<<ab, 256, 0, stream>>>(hA, ptr, crow, cnrm, b3,
                                        bng + 2 * HDIM, bnb + 2 * HDIM, bnm + 2 * HDIM, bnv + 2 * HDIM, hB);

    k_pool<<<NGRAPH, 128, 0, stream>>>(hB, seg_s, seg_e, l1W, l1b, l2W, l2b, out);
}

// Round 2
// 441.413 us; speedup vs baseline: 1.5201x; 1.5201x over previous
//
#include <hip/hip_runtime.h>
#include <cfloat>
#include <cstdint>

#define N_NODES 50000
#define N_EDGES 600000
#define HDIM    128
#define NGRAPH  2000
#define BN_EPS  1e-5f

// ---------------- CSR build ----------------

__global__ void k_init(int* degi, int* seg_s, int* seg_e) {
    int i = blockIdx.x * 256 + threadIdx.x;
    if (i < N_NODES) degi[i] = 1;                  // self-loop
    if (i < NGRAPH) { seg_s[i] = 0x7FFFFFFF; seg_e[i] = 0; }
}

__global__ void k_count(const int* __restrict__ ei, int* degi) {
    int e = blockIdx.x * 256 + threadIdx.x;
    if (e < N_EDGES) atomicAdd(&degi[ei[N_EDGES + e]], 1);   // col = targets
}

__global__ void k_dinv(const int* __restrict__ degi, float* dinv) {
    int i = blockIdx.x * 256 + threadIdx.x;
    if (i < N_NODES) dinv[i] = rsqrtf((float)degi[i]);
}

// two-level exclusive scan of degi -> ptr[0..N]
__global__ void k_scanA(const int* __restrict__ degi, int* ptr, int* bsum) {
    __shared__ int t[256];
    int i = blockIdx.x * 256 + threadIdx.x;
    int v = (i < N_NODES) ? degi[i] : 0;
    t[threadIdx.x] = v; __syncthreads();
    for (int off = 1; off < 256; off <<= 1) {
        int a = (threadIdx.x >= off) ? t[threadIdx.x - off] : 0;
        __syncthreads();
        t[threadIdx.x] += a;
        __syncthreads();
    }
    if (i < N_NODES) ptr[i + 1] = t[threadIdx.x];   // within-chunk inclusive
    if (threadIdx.x == 255) bsum[blockIdx.x] = t[255];
}

__global__ void k_scanB(const int* __restrict__ bsum, int* boff, int nb) {
    __shared__ int t[256];
    int i = threadIdx.x;
    int v = (i < nb) ? bsum[i] : 0;
    t[i] = v; __syncthreads();
    for (int off = 1; off < 256; off <<= 1) {
        int a = (i >= off) ? t[i - off] : 0;
        __syncthreads();
        t[i] += a;
        __syncthreads();
    }
    if (i < nb) boff[i] = t[i] - v;                 // exclusive
}

__global__ void k_scanC(int* ptr, const int* __restrict__ boff, int* cursor) {
    int i = blockIdx.x * 256 + threadIdx.x;
    if (i < N_NODES) {
        int val = ptr[i + 1] + boff[blockIdx.x];
        ptr[i + 1] = val;
        if (i + 1 < N_NODES) cursor[i + 1] = val;
    }
    if (i == 0) { ptr[0] = 0; cursor[0] = 0; }
}

// packed edge meta: .x = source row, .y = bitcast norm
__global__ void k_fill(const int* __restrict__ ei, const float* __restrict__ dinv,
                       int* cursor, int2* meta) {
    int e = blockIdx.x * 256 + threadIdx.x;
    if (e < N_EDGES) {
        int r = ei[e], c = ei[N_EDGES + e];
        int pos = atomicAdd(&cursor[c], 1);
        meta[pos] = make_int2(r, __float_as_int(dinv[r] * dinv[c]));
    } else if (e < N_EDGES + N_NODES) {
        int v = e - N_EDGES;
        int pos = atomicAdd(&cursor[v], 1);
        float d = dinv[v];
        meta[pos] = make_int2(v, __float_as_int(d * d));
    }
}

__global__ void k_seg(const int* __restrict__ batch, int* seg_s, int* seg_e) {
    int i = blockIdx.x * 256 + threadIdx.x;
    if (i < N_NODES) {
        int g = batch[i];
        atomicMin(&seg_s[g], i);
        atomicMax(&seg_e[g], i + 1);
    }
}

// ---------------- dense transform: hout = hin @ W ----------------
// 512 threads = 8 waves; each wave owns 8 nodes; each lane owns channels (lane, lane+64).

__global__ __launch_bounds__(512) void k_transform(const float* __restrict__ hin,
                                                   const float* __restrict__ W,
                                                   float* __restrict__ hout) {
    __shared__ float Wl[HDIM * HDIM];
    {
        const float4* W4 = (const float4*)W;
        float4* Wl4 = (float4*)Wl;
        for (int i = threadIdx.x; i < HDIM * HDIM / 4; i += 512) Wl4[i] = W4[i];
    }
    __syncthreads();
    int wave = threadIdx.x >> 6, lane = threadIdx.x & 63;
    int nb = blockIdx.x * 64 + wave * 8;
    int c0 = lane, c1 = lane + 64;

    const float* hp[8];
#pragma unroll
    for (int j = 0; j < 8; j++) {
        int nidx = nb + j; if (nidx >= N_NODES) nidx = N_NODES - 1;
        hp[j] = hin + (size_t)nidx * HDIM;
    }
    float acc0[8], acc1[8];
#pragma unroll
    for (int j = 0; j < 8; j++) { acc0[j] = 0.f; acc1[j] = 0.f; }

    for (int k = 0; k < HDIM; k++) {
        float w0 = Wl[k * HDIM + c0];
        float w1 = Wl[k * HDIM + c1];
#pragma unroll
        for (int j = 0; j < 8; j++) {
            float hv = hp[j][k];
            acc0[j] += hv * w0;
            acc1[j] += hv * w1;
        }
    }
#pragma unroll
    for (int j = 0; j < 8; j++) {
        int nidx = nb + j;
        if (nidx < N_NODES) {
            hout[(size_t)nidx * HDIM + c0] = acc0[j];
            hout[(size_t)nidx * HDIM + c1] = acc1[j];
        }
    }
}

// ---------------- aggregate + bias + BN + ReLU ----------------
// 256 threads = 8 nodes/block; 32 threads per node, float4 per thread.
// Edge loop unrolled x4: 4 independent 16B gathers in flight per thread.

__global__ __launch_bounds__(256) void k_aggregate(const float4* __restrict__ h4,
                                                   const int* __restrict__ ptr,
                                                   const int2* __restrict__ meta,
                                                   const float4* __restrict__ bias4,
                                                   const float4* __restrict__ bng4,
                                                   const float4* __restrict__ bnb4,
                                                   const float4* __restrict__ bnm4,
                                                   const float4* __restrict__ bnv4,
                                                   float4* __restrict__ hout4) {
    int v = blockIdx.x * 8 + (threadIdx.x >> 5);
    int c = threadIdx.x & 31;            // float4 column index (channels 4c..4c+3)
    if (v >= N_NODES) return;
    int e0 = ptr[v], e1 = ptr[v + 1];

    float ax = 0.f, ay = 0.f, az = 0.f, aw = 0.f;
    int j = e0;
    for (; j + 4 <= e1; j += 4) {
        int2 m0 = meta[j], m1 = meta[j + 1], m2 = meta[j + 2], m3 = meta[j + 3];
        float4 v0 = h4[(size_t)m0.x * 32 + c];
        float4 v1 = h4[(size_t)m1.x * 32 + c];
        float4 v2 = h4[(size_t)m2.x * 32 + c];
        float4 v3 = h4[(size_t)m3.x * 32 + c];
        float n0 = __int_as_float(m0.y), n1 = __int_as_float(m1.y);
        float n2 = __int_as_float(m2.y), n3 = __int_as_float(m3.y);
        ax += n0 * v0.x + n1 * v1.x + n2 * v2.x + n3 * v3.x;
        ay += n0 * v0.y + n1 * v1.y + n2 * v2.y + n3 * v3.y;
        az += n0 * v0.z + n1 * v1.z + n2 * v2.z + n3 * v3.z;
        aw += n0 * v0.w + n1 * v1.w + n2 * v2.w + n3 * v3.w;
    }
    int rem = e1 - j;                    // 0..3, clamped-masked tail (no serial chain)
    if (rem > 0) {
        int i1 = j + (rem > 1 ? 1 : 0);
        int i2 = j + (rem > 2 ? 2 : 0);
        int2 m0 = meta[j], m1 = meta[i1], m2 = meta[i2];
        float4 v0 = h4[(size_t)m0.x * 32 + c];
        float4 v1 = h4[(size_t)m1.x * 32 + c];
        float4 v2 = h4[(size_t)m2.x * 32 + c];
        float n0 = __int_as_float(m0.y);
        float n1 = (rem > 1) ? __int_as_float(m1.y) : 0.f;
        float n2 = (rem > 2) ? __int_as_float(m2.y) : 0.f;
        ax += n0 * v0.x + n1 * v1.x + n2 * v2.x;
        ay += n0 * v0.y + n1 * v1.y + n2 * v2.y;
        az += n0 * v0.z + n1 * v1.z + n2 * v2.z;
        aw += n0 * v0.w + n1 * v1.w + n2 * v2.w;
    }

    float4 bs = bias4[c], g = bng4[c], bb = bnb4[c], m = bnm4[c], vv = bnv4[c];
    float sx = g.x * rsqrtf(vv.x + BN_EPS), tx = bb.x - m.x * sx;
    float sy = g.y * rsqrtf(vv.y + BN_EPS), ty = bb.y - m.y * sy;
    float sz = g.z * rsqrtf(vv.z + BN_EPS), tz = bb.z - m.z * sz;
    float sw = g.w * rsqrtf(vv.w + BN_EPS), tw = bb.w - m.w * sw;
    float4 r;
    r.x = fmaxf((ax + bs.x) * sx + tx, 0.f);
    r.y = fmaxf((ay + bs.y) * sy + ty, 0.f);
    r.z = fmaxf((az + bs.z) * sz + tz, 0.f);
    r.w = fmaxf((aw + bs.w) * sw + tw, 0.f);
    hout4[(size_t)v * 32 + c] = r;
}

// ---------------- pool (mean|max|sum) + MLP ----------------

__global__ __launch_bounds__(128) void k_pool(const float* __restrict__ h,
                                              const int* __restrict__ seg_s,
                                              const int* __restrict__ seg_e,
                                              const float* __restrict__ l1W,
                                              const float* __restrict__ l1b,
                                              const float* __restrict__ l2W,
                                              const float* __restrict__ l2b,
                                              float* __restrict__ out) {
    __shared__ float z[3 * HDIM];
    __shared__ float red[2];
    int g = blockIdx.x, c = threadIdx.x;
    int s = seg_s[g], e = seg_e[g];
    float sum = 0.f, mx = -FLT_MAX;
    for (int i = s; i < e; i++) {
        float val = h[(size_t)i * HDIM + c];
        sum += val;
        mx = fmaxf(mx, val);
    }
    int cnt = (s < e) ? (e - s) : 0;
    if (cnt == 0) { mx = 0.f; sum = 0.f; }
    float mean = sum / (float)(cnt > 1 ? cnt : 1);
    z[c] = mean; z[HDIM + c] = mx; z[2 * HDIM + c] = sum;
    __syncthreads();
    float o = l1b[c];
    for (int k = 0; k < 3 * HDIM; k++) o += z[k] * l1W[k * HDIM + c];
    o = fmaxf(o, 0.f);
    float p = o * l2W[c];
#pragma unroll
    for (int off = 32; off; off >>= 1) p += __shfl_down(p, off, 64);
    if ((c & 63) == 0) red[c >> 6] = p;
    __syncthreads();
    if (c == 0) out[g] = red[0] + red[1] + l2b[0];
}

// ---------------- launch ----------------

extern "C" void kernel_launch(void* const* d_in, const int* in_sizes, int n_in,
                              void* d_out, int out_size, void* d_ws, size_t ws_size,
                              hipStream_t stream) {
    const float* x   = (const float*)d_in[0];
    const int*   ei  = (const int*)d_in[1];
    const int*   bat = (const int*)d_in[2];
    const float* W1  = (const float*)d_in[3];
    const float* b1  = (const float*)d_in[4];
    const float* W2  = (const float*)d_in[5];
    const float* b2  = (const float*)d_in[6];
    const float* W3  = (const float*)d_in[7];
    const float* b3  = (const float*)d_in[8];
    const float* bng = (const float*)d_in[9];
    const float* bnb = (const float*)d_in[10];
    const float* bnm = (const float*)d_in[11];
    const float* bnv = (const float*)d_in[12];
    const float* l1W = (const float*)d_in[13];
    const float* l1b = (const float*)d_in[14];
    const float* l2W = (const float*)d_in[15];
    const float* l2b = (const float*)d_in[16];
    float* out = (float*)d_out;

    char* ws = (char*)d_ws;
    size_t off = 0;
    auto alloc = [&](size_t bytes) -> char* {
        char* p = ws + off;
        off = (off + bytes + 255) & ~(size_t)255;
        return p;
    };
    int*   degi   = (int*)alloc((size_t)N_NODES * 4);
    float* dinv   = (float*)alloc((size_t)N_NODES * 4);
    int*   ptr    = (int*)alloc((size_t)(N_NODES + 1) * 4);
    int*   cursor = (int*)alloc((size_t)N_NODES * 4);
    int*   bsum   = (int*)alloc(256 * 4);
    int*   boff   = (int*)alloc(256 * 4);
    int*   seg_s  = (int*)alloc((size_t)NGRAPH * 4);
    int*   seg_e  = (int*)alloc((size_t)NGRAPH * 4);
    int2*  meta   = (int2*)alloc((size_t)(N_EDGES + N_NODES) * 8);
    float* hA     = (float*)alloc((size_t)N_NODES * HDIM * 4);
    float* hB     = (float*)alloc((size_t)N_NODES * HDIM * 4);
    (void)ws_size;

    int nblk = (N_NODES + 255) / 256;  // 196

    k_init<<<nblk, 256, 0, stream>>>(degi, seg_s, seg_e);
    k_count<<<(N_EDGES + 255) / 256, 256, 0, stream>>>(ei, degi);
    k_dinv<<<nblk, 256, 0, stream>>>(degi, dinv);
    k_scanA<<<nblk, 256, 0, stream>>>(degi, ptr, bsum);
    k_scanB<<<1, 256, 0, stream>>>(bsum, boff, nblk);
    k_scanC<<<nblk, 256, 0, stream>>>(ptr, boff, cursor);
    k_fill<<<(N_EDGES + N_NODES + 255) / 256, 256, 0, stream>>>(ei, dinv, cursor, meta);
    k_seg<<<nblk, 256, 0, stream>>>(bat, seg_s, seg_e);

    int tb = (N_NODES + 63) / 64;  // 782
    int ab = (N_NODES + 7) / 8;    // 6250

    k_transform<<<tb, 512, 0, stream>>>(x, W1, hA);
    k_aggregate<<<ab, 256, 0, stream>>>((const float4*)hA, ptr, meta, (const float4*)b1,
                                        (const float4*)(bng + 0), (const float4*)(bnb + 0),
                                        (const float4*)(bnm + 0), (const float4*)(bnv + 0),
                                        (float4*)hB);
    k_transform<<<tb, 512, 0, stream>>>(hB, W2, hA);
    k_aggregate<<<ab, 256, 0, stream>>>((const float4*)hA, ptr, meta, (const float4*)b2,
                                        (const float4*)(bng + HDIM), (const float4*)(bnb + HDIM),
                                        (const float4*)(bnm + HDIM), (const float4*)(bnv + HDIM),
                                        (float4*)hB);
    k_transform<<<tb, 512, 0, stream>>>(hB, W3, hA);
    k_aggregate<<<ab, 256, 0, stream>>>((const float4*)hA, ptr, meta, (const float4*)b3,
                                        (const float4*)(bng + 2 * HDIM), (const float4*)(bnb + 2 * HDIM),
                                        (const float4*)(bnm + 2 * HDIM), (const float4*)(bnv + 2 * HDIM),
                                        (float4*)hB);

    k_pool<<<NGRAPH, 128, 0, stream>>>(hB, seg_s, seg_e, l1W, l1b, l2W, l2b, out);
}

// Round 3
// 350.810 us; speedup vs baseline: 1.9127x; 1.2583x over previous
//
#include <hip/hip_runtime.h>
#include <cfloat>
#include <cstdint>

#define N_NODES 50000
#define N_EDGES 600000
#define HDIM    128
#define NGRAPH  2000
#define BN_EPS  1e-5f

// ---------------- CSR build ----------------

__global__ void k_init(int* degi, int* seg_s, int* seg_e) {
    int i = blockIdx.x * 256 + threadIdx.x;
    if (i < N_NODES) degi[i] = 1;                  // self-loop
    if (i < NGRAPH) { seg_s[i] = 0x7FFFFFFF; seg_e[i] = 0; }
}

__global__ void k_count(const int* __restrict__ ei, int* degi) {
    int e = blockIdx.x * 256 + threadIdx.x;
    if (e < N_EDGES) atomicAdd(&degi[ei[N_EDGES + e]], 1);   // col = targets
}

__global__ void k_dinv(const int* __restrict__ degi, float* dinv) {
    int i = blockIdx.x * 256 + threadIdx.x;
    if (i < N_NODES) dinv[i] = rsqrtf((float)degi[i]);
}

// two-level exclusive scan of degi -> ptr[0..N]
__global__ void k_scanA(const int* __restrict__ degi, int* ptr, int* bsum) {
    __shared__ int t[256];
    int i = blockIdx.x * 256 + threadIdx.x;
    int v = (i < N_NODES) ? degi[i] : 0;
    t[threadIdx.x] = v; __syncthreads();
    for (int off = 1; off < 256; off <<= 1) {
        int a = (threadIdx.x >= off) ? t[threadIdx.x - off] : 0;
        __syncthreads();
        t[threadIdx.x] += a;
        __syncthreads();
    }
    if (i < N_NODES) ptr[i + 1] = t[threadIdx.x];   // within-chunk inclusive
    if (threadIdx.x == 255) bsum[blockIdx.x] = t[255];
}

__global__ void k_scanB(const int* __restrict__ bsum, int* boff, int nb) {
    __shared__ int t[256];
    int i = threadIdx.x;
    int v = (i < nb) ? bsum[i] : 0;
    t[i] = v; __syncthreads();
    for (int off = 1; off < 256; off <<= 1) {
        int a = (i >= off) ? t[i - off] : 0;
        __syncthreads();
        t[i] += a;
        __syncthreads();
    }
    if (i < nb) boff[i] = t[i] - v;                 // exclusive
}

__global__ void k_scanC(int* ptr, const int* __restrict__ boff, int* cursor) {
    int i = blockIdx.x * 256 + threadIdx.x;
    if (i < N_NODES) {
        int val = ptr[i + 1] + boff[blockIdx.x];
        ptr[i + 1] = val;
        if (i + 1 < N_NODES) cursor[i + 1] = val;
    }
    if (i == 0) { ptr[0] = 0; cursor[0] = 0; }
}

// packed edge meta: .x = source row, .y = bitcast norm
__global__ void k_fill(const int* __restrict__ ei, const float* __restrict__ dinv,
                       int* cursor, int2* meta) {
    int e = blockIdx.x * 256 + threadIdx.x;
    if (e < N_EDGES) {
        int r = ei[e], c = ei[N_EDGES + e];
        int pos = atomicAdd(&cursor[c], 1);
        meta[pos] = make_int2(r, __float_as_int(dinv[r] * dinv[c]));
    } else if (e < N_EDGES + N_NODES) {
        int v = e - N_EDGES;
        int pos = atomicAdd(&cursor[v], 1);
        float d = dinv[v];
        meta[pos] = make_int2(v, __float_as_int(d * d));
    }
}

__global__ void k_seg(const int* __restrict__ batch, int* seg_s, int* seg_e) {
    int i = blockIdx.x * 256 + threadIdx.x;
    if (i < N_NODES) {
        int g = batch[i];
        atomicMin(&seg_s[g], i);
        atomicMax(&seg_e[g], i + 1);
    }
}

// ---------------- dense transform: hout = hin @ W ----------------
// 256 threads handle 32 nodes. h-tile (16 KB) staged in LDS coalesced; W read
// from global (L1/L2-resident, coalesced float4). Thread (nt,ct) = 4 nodes x
// 4 channels = 16 independent accumulators. Lanes sharing nt broadcast-read
// LDS (conflict-free).

__global__ __launch_bounds__(256) void k_transform(const float4* __restrict__ hin4,
                                                   const float4* __restrict__ W4,
                                                   float4* __restrict__ hout4) {
    __shared__ float4 Hs[32 * 32];   // [node][k-chunk] 16 KB
    size_t g4 = (size_t)blockIdx.x * 1024;
#pragma unroll
    for (int p = 0; p < 4; p++) {
        int idx = threadIdx.x + p * 256;
        if (g4 + idx < (size_t)N_NODES * 32) Hs[idx] = hin4[g4 + idx];
    }
    __syncthreads();

    int ct = threadIdx.x & 31;       // channel group: channels 4ct..4ct+3
    int nt = threadIdx.x >> 5;       // node group: local nodes 4nt..4nt+3
    int base = blockIdx.x * 32;

    float4 acc0 = make_float4(0.f, 0.f, 0.f, 0.f);
    float4 acc1 = acc0, acc2 = acc0, acc3 = acc0;

#pragma unroll 4
    for (int kc = 0; kc < 32; kc++) {
        float4 ha = Hs[(nt * 4 + 0) * 32 + kc];
        float4 hb = Hs[(nt * 4 + 1) * 32 + kc];
        float4 hc = Hs[(nt * 4 + 2) * 32 + kc];
        float4 hd = Hs[(nt * 4 + 3) * 32 + kc];
        float4 w0 = W4[(kc * 4 + 0) * 32 + ct];
        float4 w1 = W4[(kc * 4 + 1) * 32 + ct];
        float4 w2 = W4[(kc * 4 + 2) * 32 + ct];
        float4 w3 = W4[(kc * 4 + 3) * 32 + ct];

        acc0.x += ha.x * w0.x + ha.y * w1.x + ha.z * w2.x + ha.w * w3.x;
        acc0.y += ha.x * w0.y + ha.y * w1.y + ha.z * w2.y + ha.w * w3.y;
        acc0.z += ha.x * w0.z + ha.y * w1.z + ha.z * w2.z + ha.w * w3.z;
        acc0.w += ha.x * w0.w + ha.y * w1.w + ha.z * w2.w + ha.w * w3.w;

        acc1.x += hb.x * w0.x + hb.y * w1.x + hb.z * w2.x + hb.w * w3.x;
        acc1.y += hb.x * w0.y + hb.y * w1.y + hb.z * w2.y + hb.w * w3.y;
        acc1.z += hb.x * w0.z + hb.y * w1.z + hb.z * w2.z + hb.w * w3.z;
        acc1.w += hb.x * w0.w + hb.y * w1.w + hb.z * w2.w + hb.w * w3.w;

        acc2.x += hc.x * w0.x + hc.y * w1.x + hc.z * w2.x + hc.w * w3.x;
        acc2.y += hc.x * w0.y + hc.y * w1.y + hc.z * w2.y + hc.w * w3.y;
        acc2.z += hc.x * w0.z + hc.y * w1.z + hc.z * w2.z + hc.w * w3.z;
        acc2.w += hc.x * w0.w + hc.y * w1.w + hc.z * w2.w + hc.w * w3.w;

        acc3.x += hd.x * w0.x + hd.y * w1.x + hd.z * w2.x + hd.w * w3.x;
        acc3.y += hd.x * w0.y + hd.y * w1.y + hd.z * w2.y + hd.w * w3.y;
        acc3.z += hd.x * w0.z + hd.y * w1.z + hd.z * w2.z + hd.w * w3.z;
        acc3.w += hd.x * w0.w + hd.y * w1.w + hd.z * w2.w + hd.w * w3.w;
    }

    int n0 = base + nt * 4;
    if (n0 + 0 < N_NODES) hout4[(size_t)(n0 + 0) * 32 + ct] = acc0;
    if (n0 + 1 < N_NODES) hout4[(size_t)(n0 + 1) * 32 + ct] = acc1;
    if (n0 + 2 < N_NODES) hout4[(size_t)(n0 + 2) * 32 + ct] = acc2;
    if (n0 + 3 < N_NODES) hout4[(size_t)(n0 + 3) * 32 + ct] = acc3;
}

// ---------------- aggregate + bias + BN + ReLU ----------------
// 256 threads = 8 nodes/block; 32 threads per node, float4 per thread.
// Edge loop unrolled x4: 4 independent 16B gathers in flight per thread.

__global__ __launch_bounds__(256) void k_aggregate(const float4* __restrict__ h4,
                                                   const int* __restrict__ ptr,
                                                   const int2* __restrict__ meta,
                                                   const float4* __restrict__ bias4,
                                                   const float4* __restrict__ bng4,
                                                   const float4* __restrict__ bnb4,
                                                   const float4* __restrict__ bnm4,
                                                   const float4* __restrict__ bnv4,
                                                   float4* __restrict__ hout4) {
    int v = blockIdx.x * 8 + (threadIdx.x >> 5);
    int c = threadIdx.x & 31;            // float4 column index (channels 4c..4c+3)
    if (v >= N_NODES) return;
    int e0 = ptr[v], e1 = ptr[v + 1];

    float ax = 0.f, ay = 0.f, az = 0.f, aw = 0.f;
    int j = e0;
    for (; j + 4 <= e1; j += 4) {
        int2 m0 = meta[j], m1 = meta[j + 1], m2 = meta[j + 2], m3 = meta[j + 3];
        float4 v0 = h4[(size_t)m0.x * 32 + c];
        float4 v1 = h4[(size_t)m1.x * 32 + c];
        float4 v2 = h4[(size_t)m2.x * 32 + c];
        float4 v3 = h4[(size_t)m3.x * 32 + c];
        float n0 = __int_as_float(m0.y), n1 = __int_as_float(m1.y);
        float n2 = __int_as_float(m2.y), n3 = __int_as_float(m3.y);
        ax += n0 * v0.x + n1 * v1.x + n2 * v2.x + n3 * v3.x;
        ay += n0 * v0.y + n1 * v1.y + n2 * v2.y + n3 * v3.y;
        az += n0 * v0.z + n1 * v1.z + n2 * v2.z + n3 * v3.z;
        aw += n0 * v0.w + n1 * v1.w + n2 * v2.w + n3 * v3.w;
    }
    int rem = e1 - j;                    // 0..3, clamped-masked tail (no serial chain)
    if (rem > 0) {
        int i1 = j + (rem > 1 ? 1 : 0);
        int i2 = j + (rem > 2 ? 2 : 0);
        int2 m0 = meta[j], m1 = meta[i1], m2 = meta[i2];
        float4 v0 = h4[(size_t)m0.x * 32 + c];
        float4 v1 = h4[(size_t)m1.x * 32 + c];
        float4 v2 = h4[(size_t)m2.x * 32 + c];
        float n0 = __int_as_float(m0.y);
        float n1 = (rem > 1) ? __int_as_float(m1.y) : 0.f;
        float n2 = (rem > 2) ? __int_as_float(m2.y) : 0.f;
        ax += n0 * v0.x + n1 * v1.x + n2 * v2.x;
        ay += n0 * v0.y + n1 * v1.y + n2 * v2.y;
        az += n0 * v0.z + n1 * v1.z + n2 * v2.z;
        aw += n0 * v0.w + n1 * v1.w + n2 * v2.w;
    }

    float4 bs = bias4[c], g = bng4[c], bb = bnb4[c], m = bnm4[c], vv = bnv4[c];
    float sx = g.x * rsqrtf(vv.x + BN_EPS), tx = bb.x - m.x * sx;
    float sy = g.y * rsqrtf(vv.y + BN_EPS), ty = bb.y - m.y * sy;
    float sz = g.z * rsqrtf(vv.z + BN_EPS), tz = bb.z - m.z * sz;
    float sw = g.w * rsqrtf(vv.w + BN_EPS), tw = bb.w - m.w * sw;
    float4 r;
    r.x = fmaxf((ax + bs.x) * sx + tx, 0.f);
    r.y = fmaxf((ay + bs.y) * sy + ty, 0.f);
    r.z = fmaxf((az + bs.z) * sz + tz, 0.f);
    r.w = fmaxf((aw + bs.w) * sw + tw, 0.f);
    hout4[(size_t)v * 32 + c] = r;
}

// ---------------- pool (mean|max|sum) + MLP ----------------

__global__ __launch_bounds__(128) void k_pool(const float* __restrict__ h,
                                              const int* __restrict__ seg_s,
                                              const int* __restrict__ seg_e,
                                              const float* __restrict__ l1W,
                                              const float* __restrict__ l1b,
                                              const float* __restrict__ l2W,
                                              const float* __restrict__ l2b,
                                              float* __restrict__ out) {
    __shared__ float z[3 * HDIM];
    __shared__ float red[2];
    int g = blockIdx.x, c = threadIdx.x;
    int s = seg_s[g], e = seg_e[g];
    float sum = 0.f, mx = -FLT_MAX;
    for (int i = s; i < e; i++) {
        float val = h[(size_t)i * HDIM + c];
        sum += val;
        mx = fmaxf(mx, val);
    }
    int cnt = (s < e) ? (e - s) : 0;
    if (cnt == 0) { mx = 0.f; sum = 0.f; }
    float mean = sum / (float)(cnt > 1 ? cnt : 1);
    z[c] = mean; z[HDIM + c] = mx; z[2 * HDIM + c] = sum;
    __syncthreads();
    float o = l1b[c];
    for (int k = 0; k < 3 * HDIM; k++) o += z[k] * l1W[k * HDIM + c];
    o = fmaxf(o, 0.f);
    float p = o * l2W[c];
#pragma unroll
    for (int off = 32; off; off >>= 1) p += __shfl_down(p, off, 64);
    if ((c & 63) == 0) red[c >> 6] = p;
    __syncthreads();
    if (c == 0) out[g] = red[0] + red[1] + l2b[0];
}

// ---------------- launch ----------------

extern "C" void kernel_launch(void* const* d_in, const int* in_sizes, int n_in,
                              void* d_out, int out_size, void* d_ws, size_t ws_size,
                              hipStream_t stream) {
    const float* x   = (const float*)d_in[0];
    const int*   ei  = (const int*)d_in[1];
    const int*   bat = (const int*)d_in[2];
    const float* W1  = (const float*)d_in[3];
    const float* b1  = (const float*)d_in[4];
    const float* W2  = (const float*)d_in[5];
    const float* b2  = (const float*)d_in[6];
    const float* W3  = (const float*)d_in[7];
    const float* b3  = (const float*)d_in[8];
    const float* bng = (const float*)d_in[9];
    const float* bnb = (const float*)d_in[10];
    const float* bnm = (const float*)d_in[11];
    const float* bnv = (const float*)d_in[12];
    const float* l1W = (const float*)d_in[13];
    const float* l1b = (const float*)d_in[14];
    const float* l2W = (const float*)d_in[15];
    const float* l2b = (const float*)d_in[16];
    float* out = (float*)d_out;

    char* ws = (char*)d_ws;
    size_t off = 0;
    auto alloc = [&](size_t bytes) -> char* {
        char* p = ws + off;
        off = (off + bytes + 255) & ~(size_t)255;
        return p;
    };
    int*   degi   = (int*)alloc((size_t)N_NODES * 4);
    float* dinv   = (float*)alloc((size_t)N_NODES * 4);
    int*   ptr    = (int*)alloc((size_t)(N_NODES + 1) * 4);
    int*   cursor = (int*)alloc((size_t)N_NODES * 4);
    int*   bsum   = (int*)alloc(256 * 4);
    int*   boff   = (int*)alloc(256 * 4);
    int*   seg_s  = (int*)alloc((size_t)NGRAPH * 4);
    int*   seg_e  = (int*)alloc((size_t)NGRAPH * 4);
    int2*  meta   = (int2*)alloc((size_t)(N_EDGES + N_NODES) * 8);
    float* hA     = (float*)alloc((size_t)N_NODES * HDIM * 4);
    float* hB     = (float*)alloc((size_t)N_NODES * HDIM * 4);
    (void)ws_size;

    int nblk = (N_NODES + 255) / 256;  // 196

    k_init<<<nblk, 256, 0, stream>>>(degi, seg_s, seg_e);
    k_count<<<(N_EDGES + 255) / 256, 256, 0, stream>>>(ei, degi);
    k_dinv<<<nblk, 256, 0, stream>>>(degi, dinv);
    k_scanA<<<nblk, 256, 0, stream>>>(degi, ptr, bsum);
    k_scanB<<<1, 256, 0, stream>>>(bsum, boff, nblk);
    k_scanC<<<nblk, 256, 0, stream>>>(ptr, boff, cursor);
    k_fill<<<(N_EDGES + N_NODES + 255) / 256, 256, 0, stream>>>(ei, dinv, cursor, meta);
    k_seg<<<nblk, 256, 0, stream>>>(bat, seg_s, seg_e);

    int tb = (N_NODES + 31) / 32;  // 1563
    int ab = (N_NODES + 7) / 8;    // 6250

    k_transform<<<tb, 256, 0, stream>>>((const float4*)x, (const float4*)W1, (float4*)hA);
    k_aggregate<<<ab, 256, 0, stream>>>((const float4*)hA, ptr, meta, (const float4*)b1,
                                        (const float4*)(bng + 0), (const float4*)(bnb + 0),
                                        (const float4*)(bnm + 0), (const float4*)(bnv + 0),
                                        (float4*)hB);
    k_transform<<<tb, 256, 0, stream>>>((const float4*)hB, (const float4*)W2, (float4*)hA);
    k_aggregate<<<ab, 256, 0, stream>>>((const float4*)hA, ptr, meta, (const float4*)b2,
                                        (const float4*)(bng + HDIM), (const float4*)(bnb + HDIM),
                                        (const float4*)(bnm + HDIM), (const float4*)(bnv + HDIM),
                                        (float4*)hB);
    k_transform<<<tb, 256, 0, stream>>>((const float4*)hB, (const float4*)W3, (float4*)hA);
    k_aggregate<<<ab, 256, 0, stream>>>((const float4*)hA, ptr, meta, (const float4*)b3,
                                        (const float4*)(bng + 2 * HDIM), (const float4*)(bnb + 2 * HDIM),
                                        (const float4*)(bnm + 2 * HDIM), (const float4*)(bnv + 2 * HDIM),
                                        (float4*)hB);

    k_pool<<<NGRAPH, 128, 0, stream>>>(hB, seg_s, seg_e, l1W, l1b, l2W, l2b, out);
}

// Round 4
// 326.481 us; speedup vs baseline: 2.0552x; 1.0745x over previous
//
#include <hip/hip_runtime.h>
#include <cfloat>
#include <cstdint>

#define N_NODES 50000
#define N_EDGES 600000
#define HDIM    128
#define NGRAPH  2000
#define BN_EPS  1e-5f

// ---------------- CSR build ----------------

__global__ void k_init(int* degi, int* seg_s, int* seg_e) {
    int i = blockIdx.x * 256 + threadIdx.x;
    if (i < N_NODES) degi[i] = 1;                  // self-loop
    if (i < NGRAPH) { seg_s[i] = 0x7FFFFFFF; seg_e[i] = 0; }
}

__global__ void k_count(const int* __restrict__ ei, int* degi) {
    int e = blockIdx.x * 256 + threadIdx.x;
    if (e < N_EDGES) atomicAdd(&degi[ei[N_EDGES + e]], 1);   // col = targets
}

// two-level exclusive scan of degi -> ptr[0..N]; also emits dinv = rsqrt(deg)
__global__ void k_scanA(const int* __restrict__ degi, int* ptr, int* bsum, float* dinv) {
    __shared__ int t[256];
    int i = blockIdx.x * 256 + threadIdx.x;
    int v = (i < N_NODES) ? degi[i] : 0;
    if (i < N_NODES) dinv[i] = rsqrtf((float)v);
    t[threadIdx.x] = v; __syncthreads();
    for (int off = 1; off < 256; off <<= 1) {
        int a = (threadIdx.x >= off) ? t[threadIdx.x - off] : 0;
        __syncthreads();
        t[threadIdx.x] += a;
        __syncthreads();
    }
    if (i < N_NODES) ptr[i + 1] = t[threadIdx.x];   // within-chunk inclusive
    if (threadIdx.x == 255) bsum[blockIdx.x] = t[255];
}

__global__ void k_scanB(const int* __restrict__ bsum, int* boff, int nb) {
    __shared__ int t[256];
    int i = threadIdx.x;
    int v = (i < nb) ? bsum[i] : 0;
    t[i] = v; __syncthreads();
    for (int off = 1; off < 256; off <<= 1) {
        int a = (i >= off) ? t[i - off] : 0;
        __syncthreads();
        t[i] += a;
        __syncthreads();
    }
    if (i < nb) boff[i] = t[i] - v;                 // exclusive
}

__global__ void k_scanC(int* ptr, const int* __restrict__ boff, int* cursor) {
    int i = blockIdx.x * 256 + threadIdx.x;
    if (i < N_NODES) {
        int val = ptr[i + 1] + boff[blockIdx.x];
        ptr[i + 1] = val;
        if (i + 1 < N_NODES) cursor[i + 1] = val;
    }
    if (i == 0) { ptr[0] = 0; cursor[0] = 0; }
}

// packed edge meta: .x = source row, .y = bitcast norm
__global__ void k_fill(const int* __restrict__ ei, const float* __restrict__ dinv,
                       int* cursor, int2* meta) {
    int e = blockIdx.x * 256 + threadIdx.x;
    if (e < N_EDGES) {
        int r = ei[e], c = ei[N_EDGES + e];
        int pos = atomicAdd(&cursor[c], 1);
        meta[pos] = make_int2(r, __float_as_int(dinv[r] * dinv[c]));
    } else if (e < N_EDGES + N_NODES) {
        int v = e - N_EDGES;
        int pos = atomicAdd(&cursor[v], 1);
        float d = dinv[v];
        meta[pos] = make_int2(v, __float_as_int(d * d));
    }
}

__global__ void k_seg(const int* __restrict__ batch, int* seg_s, int* seg_e) {
    int i = blockIdx.x * 256 + threadIdx.x;
    if (i < N_NODES) {
        int g = batch[i];
        atomicMin(&seg_s[g], i);
        atomicMax(&seg_e[g], i + 1);
    }
}

// ---------------- fused GCN layer:  out = relu(BN( (S·h)·W + b ))  ----------------
// Uses associativity S·(hW) = (S·h)·W. Phase 1: gather-aggregate raw h rows for
// 32 nodes into LDS (32 threads/node, float4/thread, edge loop unroll x8 = 8
// independent 16B gathers in flight). Phase 2: 4x4 register-blocked GEMM of the
// LDS tile with W from global (L1/L2-resident), fused bias+BN+ReLU epilogue.

__global__ __launch_bounds__(256) void k_layer(const float4* __restrict__ h4,
                                               const int* __restrict__ ptr,
                                               const int2* __restrict__ meta,
                                               const float4* __restrict__ W4,
                                               const float4* __restrict__ bias4,
                                               const float4* __restrict__ bng4,
                                               const float4* __restrict__ bnb4,
                                               const float4* __restrict__ bnm4,
                                               const float4* __restrict__ bnv4,
                                               float4* __restrict__ hout4) {
    __shared__ float4 Hs[32 * 32];   // [local node][k-chunk] 16 KB
    int base = blockIdx.x * 32;
    int c = threadIdx.x & 31;        // float4 slot (channels 4c..4c+3)
    int grp = threadIdx.x >> 5;      // 8 node-groups per pass

    // ---- Phase 1: gather S·h for 32 nodes (4 passes of 8 nodes) ----
#pragma unroll
    for (int pass = 0; pass < 4; pass++) {
        int ln = pass * 8 + grp;
        int v = base + ln;
        if (v < N_NODES) {
            int e0 = ptr[v], e1 = ptr[v + 1];
            float ax = 0.f, ay = 0.f, az = 0.f, aw = 0.f;
            int j = e0;
            for (; j + 8 <= e1; j += 8) {
                int2 m[8];
#pragma unroll
                for (int i = 0; i < 8; i++) m[i] = meta[j + i];
                float4 vv[8];
#pragma unroll
                for (int i = 0; i < 8; i++) vv[i] = h4[(size_t)m[i].x * 32 + c];
#pragma unroll
                for (int i = 0; i < 8; i++) {
                    float n = __int_as_float(m[i].y);
                    ax += n * vv[i].x; ay += n * vv[i].y;
                    az += n * vv[i].z; aw += n * vv[i].w;
                }
            }
            int rem = e1 - j;            // 0..7 masked tail, no serial chain
            if (rem) {
                int2 m[8];
#pragma unroll
                for (int i = 0; i < 8; i++) m[i] = meta[j + (i < rem ? i : 0)];
                float4 vv[8];
#pragma unroll
                for (int i = 0; i < 8; i++) vv[i] = h4[(size_t)m[i].x * 32 + c];
#pragma unroll
                for (int i = 0; i < 8; i++) {
                    float n = (i < rem) ? __int_as_float(m[i].y) : 0.f;
                    ax += n * vv[i].x; ay += n * vv[i].y;
                    az += n * vv[i].z; aw += n * vv[i].w;
                }
            }
            Hs[ln * 32 + c] = make_float4(ax, ay, az, aw);
        }
    }
    __syncthreads();

    // ---- Phase 2: Hs(32x128) @ W(128x128), 4 nodes x 4 channels per thread ----
    int ct = threadIdx.x & 31;       // channel group: channels 4ct..4ct+3
    int nt = threadIdx.x >> 5;       // node group: local nodes 4nt..4nt+3

    float4 acc0 = make_float4(0.f, 0.f, 0.f, 0.f);
    float4 acc1 = acc0, acc2 = acc0, acc3 = acc0;

#pragma unroll 4
    for (int kc = 0; kc < 32; kc++) {
        float4 ha = Hs[(nt * 4 + 0) * 32 + kc];
        float4 hb = Hs[(nt * 4 + 1) * 32 + kc];
        float4 hc = Hs[(nt * 4 + 2) * 32 + kc];
        float4 hd = Hs[(nt * 4 + 3) * 32 + kc];
        float4 w0 = W4[(kc * 4 + 0) * 32 + ct];
        float4 w1 = W4[(kc * 4 + 1) * 32 + ct];
        float4 w2 = W4[(kc * 4 + 2) * 32 + ct];
        float4 w3 = W4[(kc * 4 + 3) * 32 + ct];

        acc0.x += ha.x * w0.x + ha.y * w1.x + ha.z * w2.x + ha.w * w3.x;
        acc0.y += ha.x * w0.y + ha.y * w1.y + ha.z * w2.y + ha.w * w3.y;
        acc0.z += ha.x * w0.z + ha.y * w1.z + ha.z * w2.z + ha.w * w3.z;
        acc0.w += ha.x * w0.w + ha.y * w1.w + ha.z * w2.w + ha.w * w3.w;

        acc1.x += hb.x * w0.x + hb.y * w1.x + hb.z * w2.x + hb.w * w3.x;
        acc1.y += hb.x * w0.y + hb.y * w1.y + hb.z * w2.y + hb.w * w3.y;
        acc1.z += hb.x * w0.z + hb.y * w1.z + hb.z * w2.z + hb.w * w3.z;
        acc1.w += hb.x * w0.w + hb.y * w1.w + hb.z * w2.w + hb.w * w3.w;

        acc2.x += hc.x * w0.x + hc.y * w1.x + hc.z * w2.x + hc.w * w3.x;
        acc2.y += hc.x * w0.y + hc.y * w1.y + hc.z * w2.y + hc.w * w3.y;
        acc2.z += hc.x * w0.z + hc.y * w1.z + hc.z * w2.z + hc.w * w3.z;
        acc2.w += hc.x * w0.w + hc.y * w1.w + hc.z * w2.w + hc.w * w3.w;

        acc3.x += hd.x * w0.x + hd.y * w1.x + hd.z * w2.x + hd.w * w3.x;
        acc3.y += hd.x * w0.y + hd.y * w1.y + hd.z * w2.y + hd.w * w3.y;
        acc3.z += hd.x * w0.z + hd.y * w1.z + hd.z * w2.z + hd.w * w3.z;
        acc3.w += hd.x * w0.w + hd.y * w1.w + hd.z * w2.w + hd.w * w3.w;
    }

    // fused epilogue: + bias, BN (eval), ReLU
    float4 bs = bias4[ct], g = bng4[ct], bb = bnb4[ct], m = bnm4[ct], vv = bnv4[ct];
    float sx = g.x * rsqrtf(vv.x + BN_EPS), tx = bb.x - m.x * sx;
    float sy = g.y * rsqrtf(vv.y + BN_EPS), ty = bb.y - m.y * sy;
    float sz = g.z * rsqrtf(vv.z + BN_EPS), tz = bb.z - m.z * sz;
    float sw = g.w * rsqrtf(vv.w + BN_EPS), tw = bb.w - m.w * sw;

    int n0 = base + nt * 4;
    float4 accs[4] = {acc0, acc1, acc2, acc3};
#pragma unroll
    for (int q = 0; q < 4; q++) {
        int nidx = n0 + q;
        if (nidx < N_NODES) {
            float4 a = accs[q], r;
            r.x = fmaxf((a.x + bs.x) * sx + tx, 0.f);
            r.y = fmaxf((a.y + bs.y) * sy + ty, 0.f);
            r.z = fmaxf((a.z + bs.z) * sz + tz, 0.f);
            r.w = fmaxf((a.w + bs.w) * sw + tw, 0.f);
            hout4[(size_t)nidx * 32 + ct] = r;
        }
    }
}

// ---------------- pool (mean|max|sum) + MLP ----------------

__global__ __launch_bounds__(128) void k_pool(const float* __restrict__ h,
                                              const int* __restrict__ seg_s,
                                              const int* __restrict__ seg_e,
                                              const float* __restrict__ l1W,
                                              const float* __restrict__ l1b,
                                              const float* __restrict__ l2W,
                                              const float* __restrict__ l2b,
                                              float* __restrict__ out) {
    __shared__ float z[3 * HDIM];
    __shared__ float red[2];
    int g = blockIdx.x, c = threadIdx.x;
    int s = seg_s[g], e = seg_e[g];
    float sum = 0.f, mx = -FLT_MAX;
    for (int i = s; i < e; i++) {
        float val = h[(size_t)i * HDIM + c];
        sum += val;
        mx = fmaxf(mx, val);
    }
    int cnt = (s < e) ? (e - s) : 0;
    if (cnt == 0) { mx = 0.f; sum = 0.f; }
    float mean = sum / (float)(cnt > 1 ? cnt : 1);
    z[c] = mean; z[HDIM + c] = mx; z[2 * HDIM + c] = sum;
    __syncthreads();
    float o = l1b[c];
    for (int k = 0; k < 3 * HDIM; k++) o += z[k] * l1W[k * HDIM + c];
    o = fmaxf(o, 0.f);
    float p = o * l2W[c];
#pragma unroll
    for (int off = 32; off; off >>= 1) p += __shfl_down(p, off, 64);
    if ((c & 63) == 0) red[c >> 6] = p;
    __syncthreads();
    if (c == 0) out[g] = red[0] + red[1] + l2b[0];
}

// ---------------- launch ----------------

extern "C" void kernel_launch(void* const* d_in, const int* in_sizes, int n_in,
                              void* d_out, int out_size, void* d_ws, size_t ws_size,
                              hipStream_t stream) {
    const float* x   = (const float*)d_in[0];
    const int*   ei  = (const int*)d_in[1];
    const int*   bat = (const int*)d_in[2];
    const float* W1  = (const float*)d_in[3];
    const float* b1  = (const float*)d_in[4];
    const float* W2  = (const float*)d_in[5];
    const float* b2  = (const float*)d_in[6];
    const float* W3  = (const float*)d_in[7];
    const float* b3  = (const float*)d_in[8];
    const float* bng = (const float*)d_in[9];
    const float* bnb = (const float*)d_in[10];
    const float* bnm = (const float*)d_in[11];
    const float* bnv = (const float*)d_in[12];
    const float* l1W = (const float*)d_in[13];
    const float* l1b = (const float*)d_in[14];
    const float* l2W = (const float*)d_in[15];
    const float* l2b = (const float*)d_in[16];
    float* out = (float*)d_out;

    char* ws = (char*)d_ws;
    size_t off = 0;
    auto alloc = [&](size_t bytes) -> char* {
        char* p = ws + off;
        off = (off + bytes + 255) & ~(size_t)255;
        return p;
    };
    int*   degi   = (int*)alloc((size_t)N_NODES * 4);
    float* dinv   = (float*)alloc((size_t)N_NODES * 4);
    int*   ptr    = (int*)alloc((size_t)(N_NODES + 1) * 4);
    int*   cursor = (int*)alloc((size_t)N_NODES * 4);
    int*   bsum   = (int*)alloc(256 * 4);
    int*   boff   = (int*)alloc(256 * 4);
    int*   seg_s  = (int*)alloc((size_t)NGRAPH * 4);
    int*   seg_e  = (int*)alloc((size_t)NGRAPH * 4);
    int2*  meta   = (int2*)alloc((size_t)(N_EDGES + N_NODES) * 8);
    float* hA     = (float*)alloc((size_t)N_NODES * HDIM * 4);
    float* hB     = (float*)alloc((size_t)N_NODES * HDIM * 4);
    (void)ws_size;

    int nblk = (N_NODES + 255) / 256;  // 196

    k_init<<<nblk, 256, 0, stream>>>(degi, seg_s, seg_e);
    k_count<<<(N_EDGES + 255) / 256, 256, 0, stream>>>(ei, degi);
    k_scanA<<<nblk, 256, 0, stream>>>(degi, ptr, bsum, dinv);
    k_scanB<<<1, 256, 0, stream>>>(bsum, boff, nblk);
    k_scanC<<<nblk, 256, 0, stream>>>(ptr, boff, cursor);
    k_fill<<<(N_EDGES + N_NODES + 255) / 256, 256, 0, stream>>>(ei, dinv, cursor, meta);
    k_seg<<<nblk, 256, 0, stream>>>(bat, seg_s, seg_e);

    int lb = (N_NODES + 31) / 32;  // 1563

    // layer 1: x -> hA
    k_layer<<<lb, 256, 0, stream>>>((const float4*)x, ptr, meta, (const float4*)W1,
                                    (const float4*)b1,
                                    (const float4*)(bng + 0), (const float4*)(bnb + 0),
                                    (const float4*)(bnm + 0), (const float4*)(bnv + 0),
                                    (float4*)hA);
    // layer 2: hA -> hB
    k_layer<<<lb, 256, 0, stream>>>((const float4*)hA, ptr, meta, (const float4*)W2,
                                    (const float4*)b2,
                                    (const float4*)(bng + HDIM), (const float4*)(bnb + HDIM),
                                    (const float4*)(bnm + HDIM), (const float4*)(bnv + HDIM),
                                    (float4*)hB);
    // layer 3: hB -> hA
    k_layer<<<lb, 256, 0, stream>>>((const float4*)hB, ptr, meta, (const float4*)W3,
                                    (const float4*)b3,
                                    (const float4*)(bng + 2 * HDIM), (const float4*)(bnb + 2 * HDIM),
                                    (const float4*)(bnm + 2 * HDIM), (const float4*)(bnv + 2 * HDIM),
                                    (float4*)hA);

    k_pool<<<NGRAPH, 128, 0, stream>>>(hA, seg_s, seg_e, l1W, l1b, l2W, l2b, out);
}